// Round 9
// baseline (286.945 us; speedup 1.0000x reference)
//
#include <hip/hip_runtime.h>
#include <math.h>

#define L 1024
#define SCALEF 0.125f
#define NEGF -1e30f

typedef unsigned short u16;
typedef __bf16 bf16x8 __attribute__((ext_vector_type(8)));
typedef float f32x4 __attribute__((ext_vector_type(4)));
typedef unsigned short u16x8 __attribute__((ext_vector_type(8)));
typedef unsigned short u16x4 __attribute__((ext_vector_type(4)));

#define MFMA(a, b, c) __builtin_amdgcn_mfma_f32_16x16x32_bf16(a, b, c, 0, 0, 0)

__device__ inline u16 f2b(float f) {
  union { float f; unsigned u; } v; v.f = f;
  unsigned r = v.u + 0x7fffu + ((v.u >> 16) & 1u);
  return (u16)(r >> 16);
}

// async global->LDS, 16B per lane; lds must be wave-uniform base (HW scatters lane*16)
__device__ __forceinline__ void ld16(u16* lds, const u16* g) {
  __builtin_amdgcn_global_load_lds((const __attribute__((address_space(1))) unsigned int*)g,
                                   (__attribute__((address_space(3))) unsigned int*)lds, 16, 0, 0);
}

// ---------------- prep: all fp32->bf16 casts + conv weight transposes, one launch ----------------
__global__ __launch_bounds__(256) void prep(const float* __restrict__ w, const float* __restrict__ Wqkv,
                                            const float* __restrict__ r, const float* __restrict__ Wr,
                                            const float* __restrict__ Wo,
                                            const float* __restrict__ cwq, const float* __restrict__ cwk,
                                            const float* __restrict__ cwv,
                                            u16* w_bf, u16* wqkv_bf, u16* r_bf, u16* wr_bf, u16* wo_bf,
                                            u16* wTq, u16* wTk, u16* wTv) {
  int i = blockIdx.x * 256 + threadIdx.x;
  if (i < 2621440) {
    const float* s; u16* d; int off;
    if (i < 1048576)      { s = w;    d = w_bf;    off = i; }
    else if (i < 1835008) { s = Wqkv; d = wqkv_bf; off = i - 1048576; }
    else if (i < 2097152) { s = r;    d = r_bf;    off = i - 1835008; }
    else if (i < 2359296) { s = Wr;   d = wr_bf;   off = i - 2097152; }
    else                  { s = Wo;   d = wo_bf;   off = i - 2359296; }
    float4 v = ((const float4*)s)[off];
    u16x4 o = {f2b(v.x), f2b(v.y), f2b(v.z), f2b(v.w)};
    ((u16x4*)d)[off] = o;
  } else {
    int j = i - 2621440;
    if (j < 86016) {
      int z = j / 28672, rem = j % 28672;
      const float* src = z == 0 ? cwq : z == 1 ? cwk : cwv;
      u16* dst = z == 0 ? wTq : z == 1 ? wTk : wTv;
      int tt = rem >> 12, rem2 = rem & 4095;
      int dout = rem2 >> 6, din = rem2 & 63;
      dst[rem] = f2b(src[(dout * 64 + din) * 7 + tt]);
    }
  }
}

// ---------------- 128x128 MFMA GEMM tile, async staging: C = A[M,K] * B[N,K]^T ----------------
template <int OB>
__device__ __forceinline__ void gemm_tile(u16* sA, u16* sB, const u16* A, const u16* B,
                                          void* Cp, int N, int K, int m0, int n0) {
  int t = threadIdx.x;
  int w = t >> 6, lane = t & 63;
  int q4 = lane >> 4, li = lane & 15;
  int mw = (w & 1) << 6, nw = (w >> 1) << 6;
  f32x4 acc[4][4];
#pragma unroll
  for (int i = 0; i < 4; ++i)
#pragma unroll
    for (int j = 0; j < 4; ++j) acc[i][j] = (f32x4){0.f, 0.f, 0.f, 0.f};
  int r0 = t >> 2, c0 = (t & 3) << 3;
  const u16* Ap0 = A + (size_t)(m0 + r0) * K + c0;
  const u16* Ap1 = A + (size_t)(m0 + 64 + r0) * K + c0;
  const u16* Bp0 = B + (size_t)(n0 + r0) * K + c0;
  const u16* Bp1 = B + (size_t)(n0 + 64 + r0) * K + c0;
  u16* sAw = sA + w * 512;
  u16* sBw = sB + w * 512;
  for (int kb = 0; kb < K; kb += 32) {
    __syncthreads();
    ld16(sAw, Ap0 + kb);
    ld16(sAw + 2048, Ap1 + kb);
    ld16(sBw, Bp0 + kb);
    ld16(sBw + 2048, Bp1 + kb);
    __syncthreads();
    bf16x8 fa[4], fb[4];
#pragma unroll
    for (int i = 0; i < 4; ++i) fa[i] = *(const bf16x8*)&sA[(mw + i * 16 + li) * 32 + q4 * 8];
#pragma unroll
    for (int i = 0; i < 4; ++i) fb[i] = *(const bf16x8*)&sB[(nw + i * 16 + li) * 32 + q4 * 8];
#pragma unroll
    for (int mt = 0; mt < 4; ++mt)
#pragma unroll
      for (int nt = 0; nt < 4; ++nt) acc[mt][nt] = MFMA(fa[mt], fb[nt], acc[mt][nt]);
  }
#pragma unroll
  for (int mt = 0; mt < 4; ++mt)
#pragma unroll
    for (int r = 0; r < 4; ++r) {
      size_t row = m0 + mw + mt * 16 + q4 * 4 + r;
      if (OB) {
        u16* C = (u16*)Cp;
#pragma unroll
        for (int nt = 0; nt < 4; ++nt) C[row * N + n0 + nw + nt * 16 + li] = f2b(acc[mt][nt][r]);
      } else {
        float* C = (float*)Cp;
#pragma unroll
        for (int nt = 0; nt < 4; ++nt) C[row * N + n0 + nw + nt * 16 + li] = acc[mt][nt][r];
      }
    }
}

// QKV GEMM only: 768 blocks = exactly 3.0 blocks/CU, uniform (R8: 832 blocks had
// a 64-block 4th-wave tail -> 25% serial tail at 482 TF). r GEMM moved to conv3.
__global__ __launch_bounds__(256) void gemm_qkv(const u16* __restrict__ w_bf, const u16* __restrict__ wqkv_bf,
                                                u16* __restrict__ heads) {
  __shared__ u16 sA[128 * 32];
  __shared__ u16 sB[128 * 32];
  int id = blockIdx.x;
  gemm_tile<1>(sA, sB, w_bf, wqkv_bf, heads, 3072, 1024, (id / 24) << 7, (id % 24) << 7);
}

// ---------------- 64x128 MFMA GEMM tile (higher occupancy) for W_o, fp32 out ----------------
__global__ __launch_bounds__(256) void gemm_wo(const u16* __restrict__ A, const u16* __restrict__ B,
                                               float* __restrict__ C) {
  __shared__ u16 sA[64 * 32];
  __shared__ u16 sB[128 * 32];
  int t = threadIdx.x;
  int w = t >> 6, lane = t & 63;
  int q4 = lane >> 4, li = lane & 15;
  int m0 = blockIdx.y << 6, n0 = blockIdx.x << 7;
  int nw = w << 5;
  const int N = 1024, K = 1024;
  f32x4 acc[4][2];
#pragma unroll
  for (int i = 0; i < 4; ++i)
#pragma unroll
    for (int j = 0; j < 2; ++j) acc[i][j] = (f32x4){0.f, 0.f, 0.f, 0.f};
  int r0 = t >> 2, c0 = (t & 3) << 3;
  const u16* Ap = A + (size_t)(m0 + r0) * K + c0;
  const u16* Bp0 = B + (size_t)(n0 + r0) * K + c0;
  const u16* Bp1 = B + (size_t)(n0 + 64 + r0) * K + c0;
  u16* sAw = sA + w * 512;
  u16* sBw = sB + w * 512;
  for (int kb = 0; kb < K; kb += 32) {
    __syncthreads();
    ld16(sAw, Ap + kb);
    ld16(sBw, Bp0 + kb);
    ld16(sBw + 2048, Bp1 + kb);
    __syncthreads();
    bf16x8 fa[4], fb[2];
#pragma unroll
    for (int i = 0; i < 4; ++i) fa[i] = *(const bf16x8*)&sA[(i * 16 + li) * 32 + q4 * 8];
#pragma unroll
    for (int j = 0; j < 2; ++j) fb[j] = *(const bf16x8*)&sB[(nw + j * 16 + li) * 32 + q4 * 8];
#pragma unroll
    for (int mt = 0; mt < 4; ++mt)
#pragma unroll
      for (int nt = 0; nt < 2; ++nt) acc[mt][nt] = MFMA(fa[mt], fb[nt], acc[mt][nt]);
  }
#pragma unroll
  for (int mt = 0; mt < 4; ++mt)
#pragma unroll
    for (int r = 0; r < 4; ++r) {
      size_t row = m0 + mt * 16 + q4 * 4 + r;
#pragma unroll
      for (int nt = 0; nt < 2; ++nt) C[row * N + n0 + nw + nt * 16 + li] = acc[mt][nt][r];
    }
}

// ---------------- conv1d k=7 via MFMA; z=0:q, 1:k, 2:v (v transposed [bn][d][L]);
// z=3: r-projection GEMM (64 active blocks) — rhk only needed by rel_attn (later),
// and conv3's 3072 blocks overlap the 64 GEMM blocks. Shared mem unioned. ----------------
__global__ __launch_bounds__(256) void conv3(const u16* __restrict__ x,
                                             const u16* __restrict__ wTq, const u16* __restrict__ wTk,
                                             const u16* __restrict__ wTv,
                                             const float* __restrict__ cbq, const float* __restrict__ cbk,
                                             const float* __restrict__ cbv,
                                             u16* __restrict__ qh, u16* __restrict__ kh, u16* __restrict__ vtg,
                                             const u16* __restrict__ r_bf, const u16* __restrict__ wr_bf,
                                             u16* __restrict__ rhk) {
  __shared__ u16 smem[8192];   // conv: sX[70*72]=5040 used; gemm: sA|sB = 8192
  int z = blockIdx.z;
  if (z == 3) {
    if (blockIdx.x != 0) return;
    int by = blockIdx.y;   // 0..63 -> 8x8 tiles of 128
    gemm_tile<1>(smem, smem + 4096, r_bf, wr_bf, rhk, 1024, 1024, (by >> 3) << 7, (by & 7) << 7);
    return;
  }
  u16* sX = smem;
  const u16* wT = z == 0 ? wTq : z == 1 ? wTk : wTv;
  const float* bias = z == 0 ? cbq : z == 1 ? cbk : cbv;
  int t = threadIdx.x;
  int w = t >> 6, lane = t & 63;
  int q4 = lane >> 4, li = lane & 15;
  int l0 = blockIdx.x << 6, bn = blockIdx.y;
  int b = bn >> 4, n = bn & 15;
  const u16* xb = x + b * 3072 + z * 1024 + n * 64;
  for (int e = t; e < 560; e += 256) {
    int ro = e >> 3, c = e & 7;
    int l = l0 - 3 + ro;
    u16x8 v = {0, 0, 0, 0, 0, 0, 0, 0};
    if (l >= 0 && l < L) v = *(const u16x8*)(xb + (size_t)l * 12288 + c * 8);
    *(u16x8*)&sX[ro * 72 + c * 8] = v;
  }
  bf16x8 Bw[7][2];
#pragma unroll
  for (int tt = 0; tt < 7; ++tt)
#pragma unroll
    for (int kc = 0; kc < 2; ++kc)
      Bw[tt][kc] = *(const bf16x8*)(wT + (tt * 64 + w * 16 + li) * 64 + kc * 32 + q4 * 8);
  f32x4 acc[4];
#pragma unroll
  for (int i = 0; i < 4; ++i) acc[i] = (f32x4){0.f, 0.f, 0.f, 0.f};
  __syncthreads();
#pragma unroll
  for (int tt = 0; tt < 7; ++tt)
#pragma unroll
    for (int kc = 0; kc < 2; ++kc)
#pragma unroll
      for (int mt = 0; mt < 4; ++mt) {
        bf16x8 a = *(const bf16x8*)&sX[(mt * 16 + li + tt) * 72 + kc * 32 + q4 * 8];
        acc[mt] = MFMA(a, Bw[tt][kc], acc[mt]);
      }
  float bv = bias[w * 16 + li];
  if (z < 2) {
    u16* out = z == 0 ? qh : kh;
#pragma unroll
    for (int mt = 0; mt < 4; ++mt)
#pragma unroll
      for (int r = 0; r < 4; ++r) {
        int l = l0 + mt * 16 + q4 * 4 + r;
        out[(((size_t)l * 4 + b) * 16 + n) * 64 + w * 16 + li] = f2b(acc[mt][r] + bv);
      }
  } else {
    __syncthreads();
#pragma unroll
    for (int mt = 0; mt < 4; ++mt)
#pragma unroll
      for (int r = 0; r < 4; ++r)
        sX[(w * 16 + li) * 72 + mt * 16 + q4 * 4 + r] = f2b(acc[mt][r] + bv);
    __syncthreads();
    int d = t >> 2, ch = t & 3;
    u16x8 v0 = *(u16x8*)&sX[d * 72 + ch * 16];
    u16x8 v1 = *(u16x8*)&sX[d * 72 + ch * 16 + 8];
    u16* dst = vtg + ((size_t)bn * 64 + d) * 1024 + l0 + ch * 16;
    *(u16x8*)dst = v0;
    *(u16x8*)(dst + 8) = v1;
  }
}

// ---------------- MFMA flash attention with relative shift ----------------
// R6 structure (79us) + R8 fixed-max softmax. 512 blocks, paired q-tiles p/15-p,
// uniform 17 j-tiles, register prefetch (REQUIRED for healthy VGPR allocation).
// R7 un-pairing regressed (110us). DO NOT restructure.
__global__ __launch_bounds__(256) void rel_attn(const u16* __restrict__ qh, const u16* __restrict__ kh,
                                                const u16* __restrict__ vt, const u16* __restrict__ rhk,
                                                const float* __restrict__ rwb_, const float* __restrict__ rrb_,
                                                u16* __restrict__ vec) {
  __shared__ u16 sK[64][72];
  __shared__ u16 sVt[64][72];
  __shared__ u16 sR[128][72];
  __shared__ u16 sP[4][16][72];
  int t = threadIdx.x;
  int w = t >> 6, lane = t & 63;
  int q4 = lane >> 4, li = lane & 15;
  int p = blockIdx.x, bn = blockIdx.y;
  int b = bn >> 4, n = bn & 15;
  int base_w = 48 - w * 16;
  const u16* vtb = vt + (size_t)bn * 64 * 1024;
  int er0 = t >> 3, ec = (t & 7) * 8;
  float rwbv[2][8], rrbv[2][8];
#pragma unroll
  for (int kc = 0; kc < 2; ++kc)
#pragma unroll
    for (int j = 0; j < 8; ++j) {
      int d = kc * 32 + q4 * 8 + j;
      rwbv[kc][j] = rwb_[n * 64 + d];
      rrbv[kc][j] = rrb_[n * 64 + d];
    }
  for (int half = 0; half < 2; ++half) {
    int qt = (half == 0) ? p : 15 - p;
    int i0 = qt << 6;
    bf16x8 Aw[2], Ar[2];
    {
      const u16* qrow = qh + (((size_t)(i0 + w * 16 + li) * 4 + b) * 16 + n) * 64;
#pragma unroll
      for (int kc = 0; kc < 2; ++kc) {
        bf16x8 qv = *(const bf16x8*)(qrow + kc * 32 + q4 * 8);
        bf16x8 aw, ar;
#pragma unroll
        for (int j = 0; j < 8; ++j) {
          float qf = (float)qv[j];
          aw[j] = (__bf16)(qf + rwbv[kc][j]);
          ar[j] = (__bf16)(qf + rrbv[kc][j]);
        }
        Aw[kc] = aw;
        Ar[kc] = ar;
      }
    }
    f32x4 accO[4];
#pragma unroll
    for (int i = 0; i < 4; ++i) accO[i] = (f32x4){0.f, 0.f, 0.f, 0.f};
    float lst[4];
#pragma unroll
    for (int r = 0; r < 4; ++r) lst[r] = 0.f;
    int ntile = qt + 1;
    u16x8 pK[2], pV[2], pR[4];
    {
      int j0 = 0, gB = 960 - i0;
#pragma unroll
      for (int i = 0; i < 2; ++i) {
        int row = er0 + i * 32;
        pK[i] = *(const u16x8*)(kh + (((size_t)(j0 + row) * 4 + b) * 16 + n) * 64 + ec);
        pV[i] = *(const u16x8*)(vtb + (size_t)row * 1024 + j0 + ec);
      }
#pragma unroll
      for (int i = 0; i < 4; ++i) {
        int m = er0 + i * 32;
        int g = gB + m;
        if (g > L - 1) g = L - 1;
        pR[i] = *(const u16x8*)(rhk + (size_t)g * 1024 + n * 64 + ec);
      }
    }
    for (int jt = 0; jt < ntile; ++jt) {
      __syncthreads();
#pragma unroll
      for (int i = 0; i < 2; ++i) {
        *(u16x8*)&sK[er0 + i * 32][ec] = pK[i];
        *(u16x8*)&sVt[er0 + i * 32][ec] = pV[i];
      }
#pragma unroll
      for (int i = 0; i < 4; ++i) *(u16x8*)&sR[er0 + i * 32][ec] = pR[i];
      __syncthreads();
      if (jt + 1 < ntile) {
        int j0 = (jt + 1) << 6, gB = 960 - i0 + j0;
#pragma unroll
        for (int i = 0; i < 2; ++i) {
          int row = er0 + i * 32;
          pK[i] = *(const u16x8*)(kh + (((size_t)(j0 + row) * 4 + b) * 16 + n) * 64 + ec);
          pV[i] = *(const u16x8*)(vtb + (size_t)row * 1024 + j0 + ec);
        }
#pragma unroll
        for (int i = 0; i < 4; ++i) {
          int m = er0 + i * 32;
          int g = gB + m;
          if (g > L - 1) g = L - 1;
          pR[i] = *(const u16x8*)(rhk + (size_t)g * 1024 + n * 64 + ec);
        }
      }
      int j0 = jt << 6;
      f32x4 accS[4], accG[5];
#pragma unroll
      for (int i = 0; i < 4; ++i) accS[i] = (f32x4){0.f, 0.f, 0.f, 0.f};
#pragma unroll
      for (int i = 0; i < 5; ++i) accG[i] = (f32x4){0.f, 0.f, 0.f, 0.f};
#pragma unroll
      for (int kc = 0; kc < 2; ++kc) {
#pragma unroll
        for (int nt = 0; nt < 4; ++nt) {
          bf16x8 fk = *(const bf16x8*)&sK[nt * 16 + li][kc * 32 + q4 * 8];
          accS[nt] = MFMA(Aw[kc], fk, accS[nt]);
        }
#pragma unroll
        for (int nt = 0; nt < 5; ++nt) {
          bf16x8 fr = *(const bf16x8*)&sR[base_w + nt * 16 + li][kc * 32 + q4 * 8];
          accG[nt] = MFMA(Ar[kc], fr, accG[nt]);
        }
      }
      float Sv[4][4];
#pragma unroll
      for (int nt = 0; nt < 4; ++nt)
#pragma unroll
        for (int r = 0; r < 4; ++r) {
          int il = q4 * 4 + r;
          int srcc = li + 15 - il;
          int lsrc = (lane & 48) | (srcc & 15);
          float g0 = __shfl(accG[nt][r], lsrc);
          float g1 = __shfl(accG[nt + 1][r], lsrc);
          float g = (srcc < 16) ? g0 : g1;
          Sv[nt][r] = (accS[nt][r] + g) * SCALEF;
        }
      if (jt == qt) {
#pragma unroll
        for (int nt = 0; nt < 4; ++nt)
#pragma unroll
          for (int r = 0; r < 4; ++r)
            if (j0 + nt * 16 + li > i0 + w * 16 + q4 * 4 + r) Sv[nt][r] = NEGF;
      }
      float psum[4];
#pragma unroll
      for (int r = 0; r < 4; ++r) psum[r] = 0.f;
#pragma unroll
      for (int nt = 0; nt < 4; ++nt)
#pragma unroll
        for (int r = 0; r < 4; ++r) {
          float pv = __expf(Sv[nt][r]);
          psum[r] += pv;
          sP[w][q4 * 4 + r][nt * 16 + li] = f2b(pv);
        }
#pragma unroll
      for (int r = 0; r < 4; ++r) {
        float ps = psum[r];
        ps += __shfl_xor(ps, 1);
        ps += __shfl_xor(ps, 2);
        ps += __shfl_xor(ps, 4);
        ps += __shfl_xor(ps, 8);
        lst[r] += ps;
      }
#pragma unroll
      for (int kc = 0; kc < 2; ++kc) {
        bf16x8 ap = *(const bf16x8*)&sP[w][li][kc * 32 + q4 * 8];
#pragma unroll
        for (int nt = 0; nt < 4; ++nt) {
          bf16x8 fv = *(const bf16x8*)&sVt[nt * 16 + li][kc * 32 + q4 * 8];
          accO[nt] = MFMA(ap, fv, accO[nt]);
        }
      }
    }
#pragma unroll
    for (int r = 0; r < 4; ++r) {
      int il = q4 * 4 + r;
      int ig = i0 + w * 16 + il;
      float inv = 1.0f / lst[r];
      u16* orow = vec + (((size_t)ig * 4 + b) * 16 + n) * 64;
#pragma unroll
      for (int nt = 0; nt < 4; ++nt) orow[nt * 16 + li] = f2b(accO[nt][r] * inv);
    }
  }
}

// ---------------- residual + layernorm ----------------
__global__ __launch_bounds__(256) void resid_ln(const float* __restrict__ w,
                                                const float* __restrict__ attn,
                                                const float* __restrict__ gamma,
                                                const float* __restrict__ beta,
                                                float* __restrict__ out) {
  __shared__ float ssum[4], ssq[4];
  int row = blockIdx.x, t = threadIdx.x;
  float4 xw = *(const float4*)&w[(size_t)row * 1024 + t * 4];
  float4 xa = *(const float4*)&attn[(size_t)row * 1024 + t * 4];
  float4 x = make_float4(xw.x + xa.x, xw.y + xa.y, xw.z + xa.z, xw.w + xa.w);
  float s = x.x + x.y + x.z + x.w;
  float sq = x.x * x.x + x.y * x.y + x.z * x.z + x.w * x.w;
#pragma unroll
  for (int off = 32; off > 0; off >>= 1) {
    s += __shfl_down(s, off);
    sq += __shfl_down(sq, off);
  }
  int wid = t >> 6;
  if ((t & 63) == 0) { ssum[wid] = s; ssq[wid] = sq; }
  __syncthreads();
  s = ssum[0] + ssum[1] + ssum[2] + ssum[3];
  sq = ssq[0] + ssq[1] + ssq[2] + ssq[3];
  float mean = s * (1.0f / 1024.0f);
  float var = sq * (1.0f / 1024.0f) - mean * mean;
  float rstd = rsqrtf(var + 1e-5f);
  float4 g = *(const float4*)&gamma[t * 4];
  float4 bb = *(const float4*)&beta[t * 4];
  float4 o;
  o.x = (x.x - mean) * rstd * g.x + bb.x;
  o.y = (x.y - mean) * rstd * g.y + bb.y;
  o.z = (x.z - mean) * rstd * g.z + bb.z;
  o.w = (x.w - mean) * rstd * g.w + bb.w;
  *(float4*)&out[(size_t)row * 1024 + t * 4] = o;
}

extern "C" void kernel_launch(void* const* d_in, const int* in_sizes, int n_in,
                              void* d_out, int out_size, void* d_ws, size_t ws_size,
                              hipStream_t stream) {
  const float* w     = (const float*)d_in[0];
  const float* r     = (const float*)d_in[1];
  const float* rwb   = (const float*)d_in[2];
  const float* rrb   = (const float*)d_in[3];
  const float* W_qkv = (const float*)d_in[4];
  const float* W_r   = (const float*)d_in[5];
  const float* W_o   = (const float*)d_in[6];
  const float* cwq   = (const float*)d_in[7];
  const float* cbq   = (const float*)d_in[8];
  const float* cwk   = (const float*)d_in[9];
  const float* cbk   = (const float*)d_in[10];
  const float* cwv   = (const float*)d_in[11];
  const float* cbv   = (const float*)d_in[12];
  const float* gamma = (const float*)d_in[13];
  const float* beta  = (const float*)d_in[14];
  float* outp = (float*)d_out;

  char* wsb = (char*)d_ws;
  u16*   heads   = (u16*)(wsb);                 // [4096][3072] bf16 = 24 MB
  u16*   vec     = (u16*)(wsb);                 // alias (heads dead after convs): 8 MB
  float* attnf   = (float*)(wsb + 8388608);     // 16 MB (within dead heads region)
  u16*   qh      = (u16*)(wsb + 25165824);      // 8 MB
  u16*   kh      = (u16*)(wsb + 33554432);      // 8 MB
  u16*   rhk     = (u16*)(wsb + 50331648);      // 2 MB
  u16*   w_bf    = (u16*)(wsb + 52428800);
  u16*   wqkv_bf = (u16*)(wsb + 60817408);
  u16*   r_bf    = (u16*)(wsb + 67108864);
  u16*   wr_bf   = (u16*)(wsb + 69206016);
  u16*   wo_bf   = (u16*)(wsb + 71303168);
  u16*   wTq     = (u16*)(wsb + 73400320);
  u16*   wTk     = (u16*)(wsb + 73457664);
  u16*   wTv     = (u16*)(wsb + 73515008);
  u16*   vt      = (u16*)(wsb + 73572352);      // [64][64][1024] bf16 = 8 MB

  dim3 blk(256);
  prep<<<10576, blk, 0, stream>>>(w, W_qkv, r, W_r, W_o, cwq, cwk, cwv,
                                  w_bf, wqkv_bf, r_bf, wr_bf, wo_bf, wTq, wTk, wTv);
  gemm_qkv<<<768, blk, 0, stream>>>(w_bf, wqkv_bf, heads);
  conv3<<<dim3(16, 64, 4), blk, 0, stream>>>(heads, wTq, wTk, wTv, cbq, cbk, cbv, qh, kh, vt,
                                             r_bf, wr_bf, rhk);
  rel_attn<<<dim3(8, 64), blk, 0, stream>>>(qh, kh, vt, rhk, rwb, rrb, vec);
  gemm_wo<<<dim3(8, 64), blk, 0, stream>>>(vec, wo_bf, attnf);
  resid_ln<<<4096, blk, 0, stream>>>(w, attnf, gamma, beta, outp);
}

// Round 10
// 265.240 us; speedup vs baseline: 1.0818x; 1.0818x over previous
//
#include <hip/hip_runtime.h>
#include <math.h>

#define L 1024
#define SCALEF 0.125f
#define NEGF -1e30f

typedef unsigned short u16;
typedef __bf16 bf16x8 __attribute__((ext_vector_type(8)));
typedef float f32x4 __attribute__((ext_vector_type(4)));
typedef unsigned short u16x8 __attribute__((ext_vector_type(8)));
typedef unsigned short u16x4 __attribute__((ext_vector_type(4)));

#define MFMA(a, b, c) __builtin_amdgcn_mfma_f32_16x16x32_bf16(a, b, c, 0, 0, 0)

__device__ inline u16 f2b(float f) {
  union { float f; unsigned u; } v; v.f = f;
  unsigned r = v.u + 0x7fffu + ((v.u >> 16) & 1u);
  return (u16)(r >> 16);
}

// async global->LDS, 16B per lane; lds must be wave-uniform base (HW scatters lane*16)
__device__ __forceinline__ void ld16(u16* lds, const u16* g) {
  __builtin_amdgcn_global_load_lds((const __attribute__((address_space(1))) unsigned int*)g,
                                   (__attribute__((address_space(3))) unsigned int*)lds, 16, 0, 0);
}

// ---------------- prep: all fp32->bf16 casts + conv weight transposes, one launch ----------------
__global__ __launch_bounds__(256) void prep(const float* __restrict__ w, const float* __restrict__ Wqkv,
                                            const float* __restrict__ r, const float* __restrict__ Wr,
                                            const float* __restrict__ Wo,
                                            const float* __restrict__ cwq, const float* __restrict__ cwk,
                                            const float* __restrict__ cwv,
                                            u16* w_bf, u16* wqkv_bf, u16* r_bf, u16* wr_bf, u16* wo_bf,
                                            u16* wTq, u16* wTk, u16* wTv) {
  int i = blockIdx.x * 256 + threadIdx.x;
  if (i < 2621440) {
    const float* s; u16* d; int off;
    if (i < 1048576)      { s = w;    d = w_bf;    off = i; }
    else if (i < 1835008) { s = Wqkv; d = wqkv_bf; off = i - 1048576; }
    else if (i < 2097152) { s = r;    d = r_bf;    off = i - 1835008; }
    else if (i < 2359296) { s = Wr;   d = wr_bf;   off = i - 2097152; }
    else                  { s = Wo;   d = wo_bf;   off = i - 2359296; }
    float4 v = ((const float4*)s)[off];
    u16x4 o = {f2b(v.x), f2b(v.y), f2b(v.z), f2b(v.w)};
    ((u16x4*)d)[off] = o;
  } else {
    int j = i - 2621440;
    if (j < 86016) {
      int z = j / 28672, rem = j % 28672;
      const float* src = z == 0 ? cwq : z == 1 ? cwk : cwv;
      u16* dst = z == 0 ? wTq : z == 1 ? wTk : wTv;
      int tt = rem >> 12, rem2 = rem & 4095;
      int dout = rem2 >> 6, din = rem2 & 63;
      dst[rem] = f2b(src[(dout * 64 + din) * 7 + tt]);
    }
  }
}

// ---------------- 128x128 MFMA GEMM tile, double-buffered async staging ----------------
// One barrier per K-step: prefetch ld16s issued post-barrier overlap the MFMA block;
// the vmcnt(0) drain before the NEXT barrier lands after a full compute phase.
template <int OB>
__device__ __forceinline__ void gemm_tile(u16* sA, u16* sB, const u16* A, const u16* B,
                                          void* Cp, int N, int K, int m0, int n0) {
  int t = threadIdx.x;
  int w = t >> 6, lane = t & 63;
  int q4 = lane >> 4, li = lane & 15;
  int mw = (w & 1) << 6, nw = (w >> 1) << 6;
  f32x4 acc[4][4];
#pragma unroll
  for (int i = 0; i < 4; ++i)
#pragma unroll
    for (int j = 0; j < 4; ++j) acc[i][j] = (f32x4){0.f, 0.f, 0.f, 0.f};
  int r0 = t >> 2, c0 = (t & 3) << 3;
  const u16* Ap0 = A + (size_t)(m0 + r0) * K + c0;
  const u16* Ap1 = A + (size_t)(m0 + 64 + r0) * K + c0;
  const u16* Bp0 = B + (size_t)(n0 + r0) * K + c0;
  const u16* Bp1 = B + (size_t)(n0 + 64 + r0) * K + c0;
  int wo512 = w * 512;
  // prologue: stage k=0 into buffer 0
  ld16(sA + wo512, Ap0);
  ld16(sA + wo512 + 2048, Ap1);
  ld16(sB + wo512, Bp0);
  ld16(sB + wo512 + 2048, Bp1);
  int cur = 0;
  for (int kb = 0; kb < K; kb += 32) {
    __syncthreads();           // drains vmcnt -> buf[cur] ready
    int nxt = cur ^ 1;
    if (kb + 32 < K) {
      u16* nA = sA + nxt * 4096;
      u16* nB = sB + nxt * 4096;
      ld16(nA + wo512, Ap0 + kb + 32);
      ld16(nA + wo512 + 2048, Ap1 + kb + 32);
      ld16(nB + wo512, Bp0 + kb + 32);
      ld16(nB + wo512 + 2048, Bp1 + kb + 32);
    }
    const u16* cA = sA + cur * 4096;
    const u16* cB = sB + cur * 4096;
    bf16x8 fa[4], fb[4];
#pragma unroll
    for (int i = 0; i < 4; ++i) fa[i] = *(const bf16x8*)&cA[(mw + i * 16 + li) * 32 + q4 * 8];
#pragma unroll
    for (int i = 0; i < 4; ++i) fb[i] = *(const bf16x8*)&cB[(nw + i * 16 + li) * 32 + q4 * 8];
#pragma unroll
    for (int mt = 0; mt < 4; ++mt)
#pragma unroll
      for (int nt = 0; nt < 4; ++nt) acc[mt][nt] = MFMA(fa[mt], fb[nt], acc[mt][nt]);
    cur = nxt;
  }
#pragma unroll
  for (int mt = 0; mt < 4; ++mt)
#pragma unroll
    for (int r = 0; r < 4; ++r) {
      size_t row = m0 + mw + mt * 16 + q4 * 4 + r;
      if (OB) {
        u16* C = (u16*)Cp;
#pragma unroll
        for (int nt = 0; nt < 4; ++nt) C[row * N + n0 + nw + nt * 16 + li] = f2b(acc[mt][nt][r]);
      } else {
        float* C = (float*)Cp;
#pragma unroll
        for (int nt = 0; nt < 4; ++nt) C[row * N + n0 + nw + nt * 16 + li] = acc[mt][nt][r];
      }
    }
}

// fused QKV (768 blocks) + r (64 blocks) GEMM — R8's measured-good 832-block mix
// (R9's conv3-fusion of the r GEMM regressed conv3 28->70us; tail hides better
// inside a long uniform dispatch than after short conv blocks).
__global__ __launch_bounds__(256) void gemm_stage1(const u16* __restrict__ w_bf, const u16* __restrict__ wqkv_bf,
                                                   u16* __restrict__ heads,
                                                   const u16* __restrict__ r_bf, const u16* __restrict__ wr_bf,
                                                   u16* __restrict__ rhk) {
  __shared__ u16 sA[2 * 128 * 32];
  __shared__ u16 sB[2 * 128 * 32];
  int id = blockIdx.x;
  if (id < 768) {
    gemm_tile<1>(sA, sB, w_bf, wqkv_bf, heads, 3072, 1024, (id / 24) << 7, (id % 24) << 7);
  } else {
    int j = id - 768;
    gemm_tile<1>(sA, sB, r_bf, wr_bf, rhk, 1024, 1024, (j >> 3) << 7, (j & 7) << 7);
  }
}

// ---------------- 64x128 MFMA GEMM (double-buffered) for W_o, fp32 out ----------------
__global__ __launch_bounds__(256) void gemm_wo(const u16* __restrict__ A, const u16* __restrict__ B,
                                               float* __restrict__ C) {
  __shared__ u16 sA[2 * 64 * 32];
  __shared__ u16 sB[2 * 128 * 32];
  int t = threadIdx.x;
  int w = t >> 6, lane = t & 63;
  int q4 = lane >> 4, li = lane & 15;
  int m0 = blockIdx.y << 6, n0 = blockIdx.x << 7;
  int nw = w << 5;
  const int N = 1024, K = 1024;
  f32x4 acc[4][2];
#pragma unroll
  for (int i = 0; i < 4; ++i)
#pragma unroll
    for (int j = 0; j < 2; ++j) acc[i][j] = (f32x4){0.f, 0.f, 0.f, 0.f};
  int r0 = t >> 2, c0 = (t & 3) << 3;
  const u16* Ap = A + (size_t)(m0 + r0) * K + c0;
  const u16* Bp0 = B + (size_t)(n0 + r0) * K + c0;
  const u16* Bp1 = B + (size_t)(n0 + 64 + r0) * K + c0;
  int wo512 = w * 512;
  ld16(sA + wo512, Ap);
  ld16(sB + wo512, Bp0);
  ld16(sB + wo512 + 2048, Bp1);
  int cur = 0;
  for (int kb = 0; kb < K; kb += 32) {
    __syncthreads();
    int nxt = cur ^ 1;
    if (kb + 32 < K) {
      u16* nA = sA + nxt * 2048;
      u16* nB = sB + nxt * 4096;
      ld16(nA + wo512, Ap + kb + 32);
      ld16(nB + wo512, Bp0 + kb + 32);
      ld16(nB + wo512 + 2048, Bp1 + kb + 32);
    }
    const u16* cA = sA + cur * 2048;
    const u16* cB = sB + cur * 4096;
    bf16x8 fa[4], fb[2];
#pragma unroll
    for (int i = 0; i < 4; ++i) fa[i] = *(const bf16x8*)&cA[(i * 16 + li) * 32 + q4 * 8];
#pragma unroll
    for (int j = 0; j < 2; ++j) fb[j] = *(const bf16x8*)&cB[(nw + j * 16 + li) * 32 + q4 * 8];
#pragma unroll
    for (int mt = 0; mt < 4; ++mt)
#pragma unroll
      for (int nt = 0; nt < 2; ++nt) acc[mt][nt] = MFMA(fa[mt], fb[nt], acc[mt][nt]);
    cur = nxt;
  }
#pragma unroll
  for (int mt = 0; mt < 4; ++mt)
#pragma unroll
    for (int r = 0; r < 4; ++r) {
      size_t row = m0 + mt * 16 + q4 * 4 + r;
#pragma unroll
      for (int nt = 0; nt < 2; ++nt) C[row * N + n0 + nw + nt * 16 + li] = acc[mt][nt][r];
    }
}

// ---------------- conv1d k=7 via MFMA; z=0:q, 1:k, 2:v (v written transposed [bn][d][L]) ----------------
// (R8 form — do NOT fuse foreign GEMM work in here; R9 tried and regressed.)
__global__ __launch_bounds__(256) void conv3(const u16* __restrict__ x,
                                             const u16* __restrict__ wTq, const u16* __restrict__ wTk,
                                             const u16* __restrict__ wTv,
                                             const float* __restrict__ cbq, const float* __restrict__ cbk,
                                             const float* __restrict__ cbv,
                                             u16* __restrict__ qh, u16* __restrict__ kh, u16* __restrict__ vtg) {
  __shared__ u16 sX[70 * 72];
  int z = blockIdx.z;
  const u16* wT = z == 0 ? wTq : z == 1 ? wTk : wTv;
  const float* bias = z == 0 ? cbq : z == 1 ? cbk : cbv;
  int t = threadIdx.x;
  int w = t >> 6, lane = t & 63;
  int q4 = lane >> 4, li = lane & 15;
  int l0 = blockIdx.x << 6, bn = blockIdx.y;
  int b = bn >> 4, n = bn & 15;
  const u16* xb = x + b * 3072 + z * 1024 + n * 64;
  for (int e = t; e < 560; e += 256) {
    int ro = e >> 3, c = e & 7;
    int l = l0 - 3 + ro;
    u16x8 v = {0, 0, 0, 0, 0, 0, 0, 0};
    if (l >= 0 && l < L) v = *(const u16x8*)(xb + (size_t)l * 12288 + c * 8);
    *(u16x8*)&sX[ro * 72 + c * 8] = v;
  }
  bf16x8 Bw[7][2];
#pragma unroll
  for (int tt = 0; tt < 7; ++tt)
#pragma unroll
    for (int kc = 0; kc < 2; ++kc)
      Bw[tt][kc] = *(const bf16x8*)(wT + (tt * 64 + w * 16 + li) * 64 + kc * 32 + q4 * 8);
  f32x4 acc[4];
#pragma unroll
  for (int i = 0; i < 4; ++i) acc[i] = (f32x4){0.f, 0.f, 0.f, 0.f};
  __syncthreads();
#pragma unroll
  for (int tt = 0; tt < 7; ++tt)
#pragma unroll
    for (int kc = 0; kc < 2; ++kc)
#pragma unroll
      for (int mt = 0; mt < 4; ++mt) {
        bf16x8 a = *(const bf16x8*)&sX[(mt * 16 + li + tt) * 72 + kc * 32 + q4 * 8];
        acc[mt] = MFMA(a, Bw[tt][kc], acc[mt]);
      }
  float bv = bias[w * 16 + li];
  if (z < 2) {
    u16* out = z == 0 ? qh : kh;
#pragma unroll
    for (int mt = 0; mt < 4; ++mt)
#pragma unroll
      for (int r = 0; r < 4; ++r) {
        int l = l0 + mt * 16 + q4 * 4 + r;
        out[(((size_t)l * 4 + b) * 16 + n) * 64 + w * 16 + li] = f2b(acc[mt][r] + bv);
      }
  } else {
    __syncthreads();
#pragma unroll
    for (int mt = 0; mt < 4; ++mt)
#pragma unroll
      for (int r = 0; r < 4; ++r)
        sX[(w * 16 + li) * 72 + mt * 16 + q4 * 4 + r] = f2b(acc[mt][r] + bv);
    __syncthreads();
    int d = t >> 2, ch = t & 3;
    u16x8 v0 = *(u16x8*)&sX[d * 72 + ch * 16];
    u16x8 v1 = *(u16x8*)&sX[d * 72 + ch * 16 + 8];
    u16* dst = vtg + ((size_t)bn * 64 + d) * 1024 + l0 + ch * 16;
    *(u16x8*)dst = v0;
    *(u16x8*)(dst + 8) = v1;
  }
}

// ---------------- MFMA flash attention with relative shift ----------------
// R6 structure (79us) + R8 fixed-max softmax. 512 blocks, paired q-tiles p/15-p,
// uniform 17 j-tiles, register prefetch (REQUIRED for healthy VGPR allocation).
// R7 un-pairing regressed (110us). DO NOT restructure.
__global__ __launch_bounds__(256) void rel_attn(const u16* __restrict__ qh, const u16* __restrict__ kh,
                                                const u16* __restrict__ vt, const u16* __restrict__ rhk,
                                                const float* __restrict__ rwb_, const float* __restrict__ rrb_,
                                                u16* __restrict__ vec) {
  __shared__ u16 sK[64][72];
  __shared__ u16 sVt[64][72];
  __shared__ u16 sR[128][72];
  __shared__ u16 sP[4][16][72];
  int t = threadIdx.x;
  int w = t >> 6, lane = t & 63;
  int q4 = lane >> 4, li = lane & 15;
  int p = blockIdx.x, bn = blockIdx.y;
  int b = bn >> 4, n = bn & 15;
  int base_w = 48 - w * 16;
  const u16* vtb = vt + (size_t)bn * 64 * 1024;
  int er0 = t >> 3, ec = (t & 7) * 8;
  float rwbv[2][8], rrbv[2][8];
#pragma unroll
  for (int kc = 0; kc < 2; ++kc)
#pragma unroll
    for (int j = 0; j < 8; ++j) {
      int d = kc * 32 + q4 * 8 + j;
      rwbv[kc][j] = rwb_[n * 64 + d];
      rrbv[kc][j] = rrb_[n * 64 + d];
    }
  for (int half = 0; half < 2; ++half) {
    int qt = (half == 0) ? p : 15 - p;
    int i0 = qt << 6;
    bf16x8 Aw[2], Ar[2];
    {
      const u16* qrow = qh + (((size_t)(i0 + w * 16 + li) * 4 + b) * 16 + n) * 64;
#pragma unroll
      for (int kc = 0; kc < 2; ++kc) {
        bf16x8 qv = *(const bf16x8*)(qrow + kc * 32 + q4 * 8);
        bf16x8 aw, ar;
#pragma unroll
        for (int j = 0; j < 8; ++j) {
          float qf = (float)qv[j];
          aw[j] = (__bf16)(qf + rwbv[kc][j]);
          ar[j] = (__bf16)(qf + rrbv[kc][j]);
        }
        Aw[kc] = aw;
        Ar[kc] = ar;
      }
    }
    f32x4 accO[4];
#pragma unroll
    for (int i = 0; i < 4; ++i) accO[i] = (f32x4){0.f, 0.f, 0.f, 0.f};
    float lst[4];
#pragma unroll
    for (int r = 0; r < 4; ++r) lst[r] = 0.f;
    int ntile = qt + 1;
    u16x8 pK[2], pV[2], pR[4];
    {
      int j0 = 0, gB = 960 - i0;
#pragma unroll
      for (int i = 0; i < 2; ++i) {
        int row = er0 + i * 32;
        pK[i] = *(const u16x8*)(kh + (((size_t)(j0 + row) * 4 + b) * 16 + n) * 64 + ec);
        pV[i] = *(const u16x8*)(vtb + (size_t)row * 1024 + j0 + ec);
      }
#pragma unroll
      for (int i = 0; i < 4; ++i) {
        int m = er0 + i * 32;
        int g = gB + m;
        if (g > L - 1) g = L - 1;
        pR[i] = *(const u16x8*)(rhk + (size_t)g * 1024 + n * 64 + ec);
      }
    }
    for (int jt = 0; jt < ntile; ++jt) {
      __syncthreads();
#pragma unroll
      for (int i = 0; i < 2; ++i) {
        *(u16x8*)&sK[er0 + i * 32][ec] = pK[i];
        *(u16x8*)&sVt[er0 + i * 32][ec] = pV[i];
      }
#pragma unroll
      for (int i = 0; i < 4; ++i) *(u16x8*)&sR[er0 + i * 32][ec] = pR[i];
      __syncthreads();
      if (jt + 1 < ntile) {
        int j0 = (jt + 1) << 6, gB = 960 - i0 + j0;
#pragma unroll
        for (int i = 0; i < 2; ++i) {
          int row = er0 + i * 32;
          pK[i] = *(const u16x8*)(kh + (((size_t)(j0 + row) * 4 + b) * 16 + n) * 64 + ec);
          pV[i] = *(const u16x8*)(vtb + (size_t)row * 1024 + j0 + ec);
        }
#pragma unroll
        for (int i = 0; i < 4; ++i) {
          int m = er0 + i * 32;
          int g = gB + m;
          if (g > L - 1) g = L - 1;
          pR[i] = *(const u16x8*)(rhk + (size_t)g * 1024 + n * 64 + ec);
        }
      }
      int j0 = jt << 6;
      f32x4 accS[4], accG[5];
#pragma unroll
      for (int i = 0; i < 4; ++i) accS[i] = (f32x4){0.f, 0.f, 0.f, 0.f};
#pragma unroll
      for (int i = 0; i < 5; ++i) accG[i] = (f32x4){0.f, 0.f, 0.f, 0.f};
#pragma unroll
      for (int kc = 0; kc < 2; ++kc) {
#pragma unroll
        for (int nt = 0; nt < 4; ++nt) {
          bf16x8 fk = *(const bf16x8*)&sK[nt * 16 + li][kc * 32 + q4 * 8];
          accS[nt] = MFMA(Aw[kc], fk, accS[nt]);
        }
#pragma unroll
        for (int nt = 0; nt < 5; ++nt) {
          bf16x8 fr = *(const bf16x8*)&sR[base_w + nt * 16 + li][kc * 32 + q4 * 8];
          accG[nt] = MFMA(Ar[kc], fr, accG[nt]);
        }
      }
      float Sv[4][4];
#pragma unroll
      for (int nt = 0; nt < 4; ++nt)
#pragma unroll
        for (int r = 0; r < 4; ++r) {
          int il = q4 * 4 + r;
          int srcc = li + 15 - il;
          int lsrc = (lane & 48) | (srcc & 15);
          float g0 = __shfl(accG[nt][r], lsrc);
          float g1 = __shfl(accG[nt + 1][r], lsrc);
          float g = (srcc < 16) ? g0 : g1;
          Sv[nt][r] = (accS[nt][r] + g) * SCALEF;
        }
      if (jt == qt) {
#pragma unroll
        for (int nt = 0; nt < 4; ++nt)
#pragma unroll
          for (int r = 0; r < 4; ++r)
            if (j0 + nt * 16 + li > i0 + w * 16 + q4 * 4 + r) Sv[nt][r] = NEGF;
      }
      float psum[4];
#pragma unroll
      for (int r = 0; r < 4; ++r) psum[r] = 0.f;
#pragma unroll
      for (int nt = 0; nt < 4; ++nt)
#pragma unroll
        for (int r = 0; r < 4; ++r) {
          float pv = __expf(Sv[nt][r]);
          psum[r] += pv;
          sP[w][q4 * 4 + r][nt * 16 + li] = f2b(pv);
        }
#pragma unroll
      for (int r = 0; r < 4; ++r) {
        float ps = psum[r];
        ps += __shfl_xor(ps, 1);
        ps += __shfl_xor(ps, 2);
        ps += __shfl_xor(ps, 4);
        ps += __shfl_xor(ps, 8);
        lst[r] += ps;
      }
#pragma unroll
      for (int kc = 0; kc < 2; ++kc) {
        bf16x8 ap = *(const bf16x8*)&sP[w][li][kc * 32 + q4 * 8];
#pragma unroll
        for (int nt = 0; nt < 4; ++nt) {
          bf16x8 fv = *(const bf16x8*)&sVt[nt * 16 + li][kc * 32 + q4 * 8];
          accO[nt] = MFMA(ap, fv, accO[nt]);
        }
      }
    }
#pragma unroll
    for (int r = 0; r < 4; ++r) {
      int il = q4 * 4 + r;
      int ig = i0 + w * 16 + il;
      float inv = 1.0f / lst[r];
      u16* orow = vec + (((size_t)ig * 4 + b) * 16 + n) * 64;
#pragma unroll
      for (int nt = 0; nt < 4; ++nt) orow[nt * 16 + li] = f2b(accO[nt][r] * inv);
    }
  }
}

// ---------------- residual + layernorm ----------------
__global__ __launch_bounds__(256) void resid_ln(const float* __restrict__ w,
                                                const float* __restrict__ attn,
                                                const float* __restrict__ gamma,
                                                const float* __restrict__ beta,
                                                float* __restrict__ out) {
  __shared__ float ssum[4], ssq[4];
  int row = blockIdx.x, t = threadIdx.x;
  float4 xw = *(const float4*)&w[(size_t)row * 1024 + t * 4];
  float4 xa = *(const float4*)&attn[(size_t)row * 1024 + t * 4];
  float4 x = make_float4(xw.x + xa.x, xw.y + xa.y, xw.z + xa.z, xw.w + xa.w);
  float s = x.x + x.y + x.z + x.w;
  float sq = x.x * x.x + x.y * x.y + x.z * x.z + x.w * x.w;
#pragma unroll
  for (int off = 32; off > 0; off >>= 1) {
    s += __shfl_down(s, off);
    sq += __shfl_down(sq, off);
  }
  int wid = t >> 6;
  if ((t & 63) == 0) { ssum[wid] = s; ssq[wid] = sq; }
  __syncthreads();
  s = ssum[0] + ssum[1] + ssum[2] + ssum[3];
  sq = ssq[0] + ssq[1] + ssq[2] + ssq[3];
  float mean = s * (1.0f / 1024.0f);
  float var = sq * (1.0f / 1024.0f) - mean * mean;
  float rstd = rsqrtf(var + 1e-5f);
  float4 g = *(const float4*)&gamma[t * 4];
  float4 bb = *(const float4*)&beta[t * 4];
  float4 o;
  o.x = (x.x - mean) * rstd * g.x + bb.x;
  o.y = (x.y - mean) * rstd * g.y + bb.y;
  o.z = (x.z - mean) * rstd * g.z + bb.z;
  o.w = (x.w - mean) * rstd * g.w + bb.w;
  *(float4*)&out[(size_t)row * 1024 + t * 4] = o;
}

extern "C" void kernel_launch(void* const* d_in, const int* in_sizes, int n_in,
                              void* d_out, int out_size, void* d_ws, size_t ws_size,
                              hipStream_t stream) {
  const float* w     = (const float*)d_in[0];
  const float* r     = (const float*)d_in[1];
  const float* rwb   = (const float*)d_in[2];
  const float* rrb   = (const float*)d_in[3];
  const float* W_qkv = (const float*)d_in[4];
  const float* W_r   = (const float*)d_in[5];
  const float* W_o   = (const float*)d_in[6];
  const float* cwq   = (const float*)d_in[7];
  const float* cbq   = (const float*)d_in[8];
  const float* cwk   = (const float*)d_in[9];
  const float* cbk   = (const float*)d_in[10];
  const float* cwv   = (const float*)d_in[11];
  const float* cbv   = (const float*)d_in[12];
  const float* gamma = (const float*)d_in[13];
  const float* beta  = (const float*)d_in[14];
  float* outp = (float*)d_out;

  char* wsb = (char*)d_ws;
  u16*   heads   = (u16*)(wsb);                 // [4096][3072] bf16 = 24 MB
  u16*   vec     = (u16*)(wsb);                 // alias (heads dead after convs): 8 MB
  float* attnf   = (float*)(wsb + 8388608);     // 16 MB (within dead heads region)
  u16*   qh      = (u16*)(wsb + 25165824);      // 8 MB
  u16*   kh      = (u16*)(wsb + 33554432);      // 8 MB
  u16*   rhk     = (u16*)(wsb + 50331648);      // 2 MB
  u16*   w_bf    = (u16*)(wsb + 52428800);
  u16*   wqkv_bf = (u16*)(wsb + 60817408);
  u16*   r_bf    = (u16*)(wsb + 67108864);
  u16*   wr_bf   = (u16*)(wsb + 69206016);
  u16*   wo_bf   = (u16*)(wsb + 71303168);
  u16*   wTq     = (u16*)(wsb + 73400320);
  u16*   wTk     = (u16*)(wsb + 73457664);
  u16*   wTv     = (u16*)(wsb + 73515008);
  u16*   vt      = (u16*)(wsb + 73572352);      // [64][64][1024] bf16 = 8 MB

  dim3 blk(256);
  prep<<<10576, blk, 0, stream>>>(w, W_qkv, r, W_r, W_o, cwq, cwk, cwv,
                                  w_bf, wqkv_bf, r_bf, wr_bf, wo_bf, wTq, wTk, wTv);
  gemm_stage1<<<832, blk, 0, stream>>>(w_bf, wqkv_bf, heads, r_bf, wr_bf, rhk);
  conv3<<<dim3(16, 64, 3), blk, 0, stream>>>(heads, wTq, wTk, wTv, cbq, cbk, cbv, qh, kh, vt);
  rel_attn<<<dim3(8, 64), blk, 0, stream>>>(qh, kh, vt, rhk, rwb, rrb, vec);
  gemm_wo<<<dim3(8, 64), blk, 0, stream>>>(vec, wo_bf, attnf);
  resid_ln<<<4096, blk, 0, stream>>>(w, attnf, gamma, beta, outp);
}